// Round 1
// baseline (1414.138 us; speedup 1.0000x reference)
//
#include <hip/hip_runtime.h>
#include <hip/hip_bf16.h>

// Problem constants (fixed by the reference's setup_inputs)
#define NNODES   100000
#define INF      256
#define OUTF     128
#define NLAYERS  3        // n_layers input is a device scalar, constant 3 per spec

// ---------------- CSR build ----------------

__global__ void hist_kernel(const int* __restrict__ row, int* __restrict__ cnt, int E) {
    int e = blockIdx.x * blockDim.x + threadIdx.x;
    if (e < E) atomicAdd(&cnt[row[e]], 1);
}

// Single-block exclusive scan over n counts -> rowptr[0..n], rowptr[n] = total.
__global__ __launch_bounds__(1024) void scan_kernel(const int* __restrict__ cnt,
                                                    int* __restrict__ rowptr, int n) {
    const int T = 1024;
    int tid = threadIdx.x;
    int chunk = (n + T - 1) / T;
    int s0 = tid * chunk;
    int s1 = s0 + chunk; if (s1 > n) s1 = n; if (s0 > n) s0 = n;
    int sum = 0;
    for (int i = s0; i < s1; ++i) sum += cnt[i];
    __shared__ int sums[T];
    sums[tid] = sum;
    __syncthreads();
    // Hillis-Steele inclusive scan
    for (int off = 1; off < T; off <<= 1) {
        int v = (tid >= off) ? sums[tid - off] : 0;
        __syncthreads();
        sums[tid] += v;
        __syncthreads();
    }
    int run = (tid == 0) ? 0 : sums[tid - 1];   // exclusive prefix of this chunk
    for (int i = s0; i < s1; ++i) { rowptr[i] = run; run += cnt[i]; }
    if (tid == T - 1) rowptr[n] = run;          // total == E
}

__global__ void copy_kernel(const int* __restrict__ src, int* __restrict__ dst, int n) {
    int i = blockIdx.x * blockDim.x + threadIdx.x;
    if (i < n) dst[i] = src[i];
}

__global__ void scatter_kernel(const int* __restrict__ row, const int* __restrict__ col,
                               const float* __restrict__ vals, int* __restrict__ wofs,
                               int* __restrict__ ecol, float* __restrict__ eval, int E) {
    int e = blockIdx.x * blockDim.x + threadIdx.x;
    if (e < E) {
        int r = row[e];
        int p = atomicAdd(&wofs[r], 1);
        ecol[p] = col[e];
        eval[p] = vals[e];
    }
}

// ---------------- dense linear: z = x * W^T + b ----------------
// Tile: 32 nodes x 128 outs, K=256 in chunks of 64. Block 256 threads.
// Thread owns 4 nodes (consecutive) x 4 outs (stride 32): acc[4][4].
// LDS pad 65: inner-loop Ws reads hit bank (oi+k)%32 across lanes -> conflict-free;
// xs reads are 2-address broadcasts -> free.
__global__ __launch_bounds__(256) void gemm_kernel(const float* __restrict__ x,
                                                   const float* __restrict__ W,
                                                   const float* __restrict__ b,
                                                   float* __restrict__ z, int M) {
    __shared__ float xs[32][65];
    __shared__ float Ws[128][65];
    int tid = threadIdx.x;
    int n0  = blockIdx.x * 32;
    int oi  = tid & 31;          // out lane: o = oi + 32*j
    int ni  = (tid >> 5) * 4;    // node base: n = ni + i

    float bo[4];
#pragma unroll
    for (int j = 0; j < 4; ++j) bo[j] = b[oi + 32 * j];
    float acc[4][4];
#pragma unroll
    for (int i = 0; i < 4; ++i)
#pragma unroll
        for (int j = 0; j < 4; ++j) acc[i][j] = bo[j];

    for (int k0 = 0; k0 < INF; k0 += 64) {
        {   // stage x tile: 32 rows x 64 cols; thread -> 8 consecutive floats
            int rrow = tid >> 3, kk = (tid & 7) * 8;
            int nn = n0 + rrow; if (nn >= M) nn = M - 1;
            const float* src = x + (size_t)nn * INF + k0 + kk;
            float4 a0 = ((const float4*)src)[0];
            float4 a1 = ((const float4*)src)[1];
            xs[rrow][kk + 0] = a0.x; xs[rrow][kk + 1] = a0.y;
            xs[rrow][kk + 2] = a0.z; xs[rrow][kk + 3] = a0.w;
            xs[rrow][kk + 4] = a1.x; xs[rrow][kk + 5] = a1.y;
            xs[rrow][kk + 6] = a1.z; xs[rrow][kk + 7] = a1.w;
        }
        {   // stage W tile: 128 rows x 64 cols; thread -> 32 consecutive floats
            int rrow = tid >> 1, kk = (tid & 1) * 32;
            const float* src = W + (size_t)rrow * INF + k0 + kk;
#pragma unroll
            for (int t = 0; t < 8; ++t) {
                float4 a = ((const float4*)src)[t];
                Ws[rrow][kk + 4 * t + 0] = a.x; Ws[rrow][kk + 4 * t + 1] = a.y;
                Ws[rrow][kk + 4 * t + 2] = a.z; Ws[rrow][kk + 4 * t + 3] = a.w;
            }
        }
        __syncthreads();
#pragma unroll 4
        for (int k = 0; k < 64; ++k) {
            float xv[4], wv[4];
#pragma unroll
            for (int i = 0; i < 4; ++i) xv[i] = xs[ni + i][k];
#pragma unroll
            for (int j = 0; j < 4; ++j) wv[j] = Ws[oi + 32 * j][k];
#pragma unroll
            for (int i = 0; i < 4; ++i)
#pragma unroll
                for (int j = 0; j < 4; ++j) acc[i][j] += xv[i] * wv[j];
        }
        __syncthreads();
    }
#pragma unroll
    for (int i = 0; i < 4; ++i) {
        int nn = n0 + ni + i;
        if (nn < M) {
#pragma unroll
            for (int j = 0; j < 4; ++j)
                z[(size_t)nn * OUTF + oi + 32 * j] = acc[i][j];
        }
    }
}

// ---------------- SpMM (CSR, gather form) ----------------
// One block (128 threads) per row. 4 edge-groups of 32 lanes; each lane owns
// 4 consecutive feats (float4 gather, fully coalesced 512B per group).
__global__ __launch_bounds__(128) void spmm_kernel(const int* __restrict__ rowptr,
                                                   const int* __restrict__ ecol,
                                                   const float* __restrict__ eval,
                                                   const float* __restrict__ zin,
                                                   float* __restrict__ zout) {
    int r   = blockIdx.x;
    int tid = threadIdx.x;
    int g   = tid >> 5;        // edge group 0..3
    int l   = tid & 31;        // lane in group
    int f   = l * 4;           // feature base
    int start = rowptr[r], end = rowptr[r + 1];

    float4 acc = make_float4(0.f, 0.f, 0.f, 0.f);
    for (int e = start + g; e < end; e += 4) {
        int   c = ecol[e];
        float v = eval[e];
        float4 zc = *(const float4*)(zin + (size_t)c * OUTF + f);
        acc.x += v * zc.x; acc.y += v * zc.y;
        acc.z += v * zc.z; acc.w += v * zc.w;
    }
    __shared__ float red[4][OUTF];
    *(float4*)&red[g][f] = acc;
    __syncthreads();
    if (tid < OUTF) {
        float s = red[0][tid] + red[1][tid] + red[2][tid] + red[3][tid];
        zout[(size_t)r * OUTF + tid] = s;
    }
}

// ---------------- launch ----------------

extern "C" void kernel_launch(void* const* d_in, const int* in_sizes, int n_in,
                              void* d_out, int out_size, void* d_ws, size_t ws_size,
                              hipStream_t stream) {
    const float* x    = (const float*)d_in[0];
    const int*   row  = (const int*)d_in[1];
    const int*   col  = (const int*)d_in[2];
    const float* vals = (const float*)d_in[3];
    const float* W    = (const float*)d_in[4];
    const float* b    = (const float*)d_in[5];
    float* out = (float*)d_out;

    const int M = in_sizes[0] / INF;     // 100000
    const int E = in_sizes[1];           // 3200000

    // workspace layout
    float* zA     = (float*)d_ws;                      // M*OUTF floats
    int*   cnt    = (int*)(zA + (size_t)M * OUTF);     // M
    int*   rowptr = cnt + M;                           // M+1
    int*   wofs   = rowptr + (M + 1);                  // M
    int*   ecol   = wofs + M;                          // E
    float* eval   = (float*)(ecol + E);                // E

    // 1. CSR build
    hipMemsetAsync(cnt, 0, (size_t)M * sizeof(int), stream);
    hist_kernel<<<(E + 255) / 256, 256, 0, stream>>>(row, cnt, E);
    scan_kernel<<<1, 1024, 0, stream>>>(cnt, rowptr, M);
    copy_kernel<<<(M + 255) / 256, 256, 0, stream>>>(rowptr, wofs, M);
    scatter_kernel<<<(E + 255) / 256, 256, 0, stream>>>(row, col, vals, wofs, ecol, eval, E);

    // 2. linear: zA = x W^T + b
    gemm_kernel<<<(M + 31) / 32, 256, 0, stream>>>(x, W, b, zA, M);

    // 3. three SpMM layers, ping-pong zA <-> out
    spmm_kernel<<<M, 128, 0, stream>>>(rowptr, ecol, eval, zA, out);   // L1
    spmm_kernel<<<M, 128, 0, stream>>>(rowptr, ecol, eval, out, zA);   // L2
    spmm_kernel<<<M, 128, 0, stream>>>(rowptr, ecol, eval, zA, out);   // L3
}